// Round 4
// baseline (218.199 us; speedup 1.0000x reference)
//
#include <hip/hip_runtime.h>

// CapsuleLayer dynamic routing, MI355X. R4.
// B=32, I=2048, K=16, O=D*A=512 (D=32, A=16), num_routing=3.
//
// Key algebra: l2[b,i,d] = l1 + sum_a V*act1 = sum_a V[b,i,d,a]*(act0+act1)[b,d,a]
// -> pass2 == pass1 with asum = act0+act1 (saves a dot + 32 VGPRs).
//
// Sweep: 512 wgs x 512 thr (8 waves cover all 32 b's, 4 b each; W staged ONCE).
// Lane owns o = lane*8 .. lane*8+7 (d = lane>>1, h = lane&1):
//   - a-half combine: shfl_xor(.,1); softmax over D: shfl_xor {2,4,8,16,32}
// sW is ROW-MAJOR W[i] (identity staging) -> global_load_lds width-16 DMA;
// hot loop reads 2x ds_read_b128 at k*2048B + lane*32B (conflict-free).
// x loaded via wave-uniform base (SGPR path). __launch_bounds__(512,4)
// pins VGPR<=128 so 2 wgs/CU co-reside to cover barrier drains.

#define B_  32
#define I_  2048
#define K_  16
#define O_  512
#define NG_ 512   // i-groups = grid size (partial leading dim)
#define IC_ 4     // i's per group

typedef const __attribute__((address_space(1))) uint32_t* gp_t;
typedef __attribute__((address_space(3))) uint32_t* lp_t;

template<int PASS>
__global__ __launch_bounds__(512, 4)
void sweep_kernel(const float* __restrict__ x, const float* __restrict__ W,
                  const float* __restrict__ act0_g, const float* __restrict__ act1_g,
                  float* __restrict__ partial)
{
    const int tid  = threadIdx.x;
    const int lane = tid & 63;
    const int wave = tid >> 6;              // 0..7
    const int ig   = blockIdx.x;
    const int obase = lane * 8;

    // wave-uniform batch base (SGPR path for x loads)
    const int wv    = __builtin_amdgcn_readfirstlane(wave);
    const int bbase = wv * 4;

    __shared__ float sW[K_ * O_];           // 32 KB, row-major W[i]

    float facc[4][8];
    #pragma unroll
    for (int bb = 0; bb < 4; ++bb)
        #pragma unroll
        for (int j = 0; j < 8; ++j) facc[bb][j] = 0.f;

    float as[4][8];                         // act0 (pass1) or act0+act1 (pass2)
    if (PASS >= 1) {
        #pragma unroll
        for (int bb = 0; bb < 4; ++bb) {
            const float4* p0 = (const float4*)(act0_g + (bbase + bb) * O_ + obase);
            float4 f0 = p0[0], f1 = p0[1];
            as[bb][0]=f0.x; as[bb][1]=f0.y; as[bb][2]=f0.z; as[bb][3]=f0.w;
            as[bb][4]=f1.x; as[bb][5]=f1.y; as[bb][6]=f1.z; as[bb][7]=f1.w;
            if (PASS == 2) {
                const float4* p1 = (const float4*)(act1_g + (bbase + bb) * O_ + obase);
                float4 g0 = p1[0], g1 = p1[1];
                as[bb][0]+=g0.x; as[bb][1]+=g0.y; as[bb][2]+=g0.z; as[bb][3]+=g0.w;
                as[bb][4]+=g1.x; as[bb][5]+=g1.y; as[bb][6]+=g1.z; as[bb][7]+=g1.w;
            }
        }
    }

    for (int ii = 0; ii < IC_; ++ii) {
        const int i = ig * IC_ + ii;
        __syncthreads();   // protect prior iteration's LDS reads
        // stage W[i] row-major via direct-to-LDS DMA: 4 insts/wave, 16B/lane
        {
            const float* gsrc = W + (size_t)i * (K_ * O_);
            #pragma unroll
            for (int q = 0; q < 4; ++q) {
                const int fb = (wave * 4 + q) * 64;      // float4 base index
                __builtin_amdgcn_global_load_lds(
                    (gp_t)(gsrc + 4 * (fb + lane)),
                    (lp_t)(&sW[4 * fb]), 16, 0, 0);
            }
        }
        // x for this wave's 4 b's: wave-uniform loads
        float xs[4][16];
        #pragma unroll
        for (int bb = 0; bb < 4; ++bb) {
            const float4* xp = (const float4*)(x + ((size_t)(bbase + bb) * I_ + i) * K_);
            #pragma unroll
            for (int q = 0; q < 4; ++q) {
                float4 v = xp[q];
                xs[bb][4*q+0]=v.x; xs[bb][4*q+1]=v.y; xs[bb][4*q+2]=v.z; xs[bb][4*q+3]=v.w;
            }
        }
        __syncthreads();

        // V[bb][j]: 2 ds_read_b128 per k
        float V[4][8];
        #pragma unroll
        for (int bb = 0; bb < 4; ++bb)
            #pragma unroll
            for (int j = 0; j < 8; ++j) V[bb][j] = 0.f;
        #pragma unroll
        for (int k = 0; k < K_; ++k) {
            const float4 w0 = *(const float4*)&sW[k * O_ + obase];
            const float4 w1 = *(const float4*)&sW[k * O_ + obase + 4];
            const float w[8] = {w0.x, w0.y, w0.z, w0.w, w1.x, w1.y, w1.z, w1.w};
            #pragma unroll
            for (int bb = 0; bb < 4; ++bb) {
                const float xb = xs[bb][k];
                #pragma unroll
                for (int j = 0; j < 8; ++j) V[bb][j] = fmaf(xb, w[j], V[bb][j]);
            }
        }

        #pragma unroll
        for (int bb = 0; bb < 4; ++bb) {
            if (PASS == 0) {
                #pragma unroll
                for (int j = 0; j < 8; ++j) facc[bb][j] += V[bb][j];
            } else {
                float lg = 0.f;
                #pragma unroll
                for (int j = 0; j < 8; ++j) lg = fmaf(V[bb][j], as[bb][j], lg);
                lg += __shfl_xor(lg, 1);        // combine the two a-halves
                // softmax over 32 d's (no max-sub: logits small, f32-safe)
                const float e = __expf(lg);
                float s = e;
                s += __shfl_xor(s, 2);
                s += __shfl_xor(s, 4);
                s += __shfl_xor(s, 8);
                s += __shfl_xor(s, 16);
                s += __shfl_xor(s, 32);
                const float r = e * __builtin_amdgcn_rcpf(s);
                #pragma unroll
                for (int j = 0; j < 8; ++j)
                    facc[bb][j] = fmaf(r, V[bb][j], facc[bb][j]);
            }
        }
    }

    // flush per-ig partials
    #pragma unroll
    for (int bb = 0; bb < 4; ++bb) {
        const int b = bbase + bb;
        float4* dst = (float4*)(partial + ((size_t)ig * B_ + b) * O_ + obase);
        dst[0] = make_float4(facc[bb][0], facc[bb][1], facc[bb][2], facc[bb][3]);
        dst[1] = make_float4(facc[bb][4], facc[bb][5], facc[bb][6], facc[bb][7]);
    }
}

// sum NG_ partials -> *scale + bias -> squash over A -> out
// 256 wgs x 256 thr; wg covers 64 g's (16 float4) x 16 w-slices of 32.
__global__ __launch_bounds__(256)
void reduce_squash(const float* __restrict__ partial, const float* __restrict__ bias,
                   float scale, float* __restrict__ out)
{
    const int t     = threadIdx.x;
    const int quad  = t & 15;       // which float4 of the wg's 64 g's
    const int slice = t >> 4;       // 0..15, w-slice of 32
    const int gbase = blockIdx.x * 64;
    const float4* src = (const float4*)partial + (gbase >> 2) + quad;

    float4 acc = make_float4(0.f, 0.f, 0.f, 0.f);
    #pragma unroll 8
    for (int w = slice * 32; w < slice * 32 + 32; ++w) {
        float4 v = src[(size_t)w * (B_ * O_ / 4)];
        acc.x += v.x; acc.y += v.y; acc.z += v.z; acc.w += v.w;
    }
    __shared__ float4 red[256];
    red[t] = acc;
    __syncthreads();
    if (t < 64) {
        float s = 0.f;
        #pragma unroll
        for (int sl = 0; sl < 16; ++sl)
            s += ((const float*)&red[sl * 16 + (t >> 2)])[t & 3];
        const float p = fmaf(s, scale, bias[(gbase + t) & (O_ - 1)]);
        float nn = p * p;
        nn += __shfl_xor(nn, 1);
        nn += __shfl_xor(nn, 2);
        nn += __shfl_xor(nn, 4);
        nn += __shfl_xor(nn, 8);
        out[gbase + t] = p * sqrtf(nn) / (1.f + nn);
    }
}

extern "C" void kernel_launch(void* const* d_in, const int* in_sizes, int n_in,
                              void* d_out, int out_size, void* d_ws, size_t ws_size,
                              hipStream_t stream) {
    const float* x    = (const float*)d_in[0];   // [32,2048,16]
    const float* W    = (const float*)d_in[1];   // [2048,16,512]
    const float* bias = (const float*)d_in[2];   // [512]
    float* out = (float*)d_out;                  // [32,512]

    float* partial = (float*)d_ws;                       // NG_*32*512 f32 = 33.5 MB
    float* act0    = partial + (size_t)NG_ * B_ * O_;    // 64 KB
    float* act1    = act0 + B_ * O_;                     // 64 KB

    sweep_kernel<0><<<NG_, 512, 0, stream>>>(x, W, nullptr, nullptr, partial);
    reduce_squash<<<256, 256, 0, stream>>>(partial, bias, 1.f / 32.f, act0);
    sweep_kernel<1><<<NG_, 512, 0, stream>>>(x, W, act0, nullptr, partial);
    reduce_squash<<<256, 256, 0, stream>>>(partial, bias, 1.f, act1);
    sweep_kernel<2><<<NG_, 512, 0, stream>>>(x, W, act0, act1, partial);
    reduce_squash<<<256, 256, 0, stream>>>(partial, bias, 1.f, out);
}